// Round 9
// baseline (455.661 us; speedup 1.0000x reference)
//
#include <hip/hip_runtime.h>

typedef __attribute__((ext_vector_type(8))) short bf16x8;
typedef __attribute__((ext_vector_type(4))) float f32x4;

__device__ __forceinline__ float b2f(ushort s) { return __uint_as_float(((uint)s) << 16); }
__device__ __forceinline__ ushort f2b(float f) {
  uint u = __float_as_uint(f);
  u += 0x7fff + ((u >> 16) & 1);   // RNE
  return (ushort)(u >> 16);
}

__device__ __forceinline__ void store_h(float* p, float v) { *p = v; }
__device__ __forceinline__ void store_h(ushort* p, float v) { *p = f2b(v); }

__device__ __forceinline__ float sigm_fast(float x) { return 1.f / (1.f + __expf(-x)); }
__device__ __forceinline__ float tanh_fast(float c) {
  float e = __expf(-2.f * fabsf(c));
  float t = (1.f - e) / (1.f + e);
  return copysignf(t, c);
}

// ---------------- transpose+cast: in (R x C) f32 -> out (C x R) bf16 ----------------
__global__ void transpose_kernel(const float* __restrict__ in, ushort* __restrict__ out,
                                 int R, int C) {
  __shared__ ushort tile[32][33];
  int bc = blockIdx.x << 5;
  int br = blockIdx.y << 5;
  int tx = threadIdx.x & 31;
  int ty = threadIdx.x >> 5;  // 0..7
#pragma unroll
  for (int i = 0; i < 32; i += 8)
    tile[ty + i][tx] = f2b(in[(size_t)(br + ty + i) * C + bc + tx]);
  __syncthreads();
#pragma unroll
  for (int i = 0; i < 32; i += 8)
    out[(size_t)(bc + ty + i) * R + br + tx] = tile[tx][ty + i];
}

// ---------------- embedding gather+cast ----------------
__global__ void embed_kernel(const int* __restrict__ tok, const float* __restrict__ emb,
                             ushort* __restrict__ x) {
  int tid = threadIdx.x;
  int r = (blockIdx.x << 2) + (tid >> 6);
  int c = (tid & 63) << 3;
  int t = tok[r];
  const float* src = emb + ((size_t)t << 9) + c;
  float4 a = *(const float4*)src;
  float4 b = *(const float4*)(src + 4);
  uint4 o;
  o.x = (uint)f2b(a.x) | ((uint)f2b(a.y) << 16);
  o.y = (uint)f2b(a.z) | ((uint)f2b(a.w) << 16);
  o.z = (uint)f2b(b.x) | ((uint)f2b(b.y) << 16);
  o.w = (uint)f2b(b.z) | ((uint)f2b(b.w) << 16);
  *(uint4*)(x + ((size_t)r << 9) + c) = o;
}

// ---------------- GEMM v4: 256x256 tile, BK=64, 2-buffer counted-vmcnt pipeline ------
// C(MxN) bf16 = A(MxK) * BT(NxK), 512 threads = 8 waves (2M x 4N), per-wave 128x64 out.
// Explicit fragment double-buffer (afA/bgA vs afB/bgB, static indices): kk1's 12
// ds_read_b128 overlap kk0's 32-MFMA cluster. Needs ~240 VGPR.
// R8 lesson (rule #15): __launch_bounds__(512,2) made hipcc cap VGPR at 128 (2 blocks/CU
// = 4 waves/SIMD) -> ~112 regs of scratch spill (WRITE_SIZE +15MB), MfmaUtil 26%.
// LDS (128 KiB) forces 1 block/CU anyway -> (512,1) unlocks the 256-VGPR budget.
// LDS: 2 x 64 KiB; staging global_load_lds w=16, linear dest + inverse-swizzled src;
// reads swizzled byte ^= (row&7)<<4 (0 conflicts). XCD-chunked 8x4 supertile mapping.
__global__ __launch_bounds__(512, 1) void gemm_bt4_kernel(
    const ushort* __restrict__ A, const ushort* __restrict__ BT,
    ushort* __restrict__ C, int M, int N, int K) {
  __shared__ char lds[2][65536];  // per buf: A bytes [0,32768), B bytes [32768,65536)
  const int tid = threadIdx.x;
  const int lane = tid & 63;
  const int wave = tid >> 6;  // 0..7
  const int wr = wave >> 2;   // 0..1
  const int wc = wave & 3;    // 0..3

  // supertile mapping (requires gridDim.x % 256 == 0; true for 1024 and 768)
  const int xcd = blockIdx.x & 7;
  const int l = blockIdx.x >> 3;
  const int s = xcd * (gridDim.x >> 8) + (l >> 5);  // supertile id (8mt x 4nt)
  const int uu = l & 31;
  const int mt = ((s & 7) << 3) + (uu & 7);
  const int nt = ((s >> 3) << 2) + (uu >> 3);
  const int m0 = mt << 8;
  const int n0 = nt << 8;
  const int NT = K >> 6;

  // t-invariant swizzled LDS byte offsets for the two kk phases
  int aoff0[8], boff0[4], aoff1[8], boff1[4];
  {
    const int k0b = (((lane >> 4) << 3)) << 1;
    const int k1b = ((32 + ((lane >> 4) << 3))) << 1;
#pragma unroll
    for (int mi = 0; mi < 8; ++mi) {
      int row = (wr << 7) + (mi << 4) + (lane & 15);
      int swz = (row & 7) << 4;
      aoff0[mi] = ((row << 7) + k0b) ^ swz;
      aoff1[mi] = ((row << 7) + k1b) ^ swz;
    }
#pragma unroll
    for (int ni = 0; ni < 4; ++ni) {
      int row = (wc << 6) + (ni << 4) + (lane & 15);
      int swz = (row & 7) << 4;
      boff0[ni] = 32768 + (((row << 7) + k0b) ^ swz);
      boff1[ni] = 32768 + (((row << 7) + k1b) ^ swz);
    }
  }

  auto stage = [&](int t, int p) {
    const ushort* Asrc = A + (size_t)m0 * K + (t << 6);
    const ushort* Bsrc = BT + (size_t)n0 * K + (t << 6);
#pragma unroll
    for (int i = 0; i < 8; ++i) {
      int sub = i & 3;
      int off = (sub << 13) + (tid << 4);             // byte within 32KiB region
      int row = off >> 7;                             // 0..255
      int col = ((off & 127) ^ ((row & 7) << 4)) >> 1;
      const ushort* src = ((i < 4) ? Asrc : Bsrc) + (size_t)row * K + col;
      char* dst = lds[p] + ((i < 4) ? 0 : 32768) + (sub << 13) + (wave << 10);
      __builtin_amdgcn_global_load_lds(
          (const __attribute__((address_space(1))) void*)src,
          (__attribute__((address_space(3))) void*)dst, 16, 0, 0);
    }
  };

  f32x4 acc[8][4];
#pragma unroll
  for (int i = 0; i < 8; ++i)
#pragma unroll
    for (int j = 0; j < 4; ++j) acc[i][j] = (f32x4){0.f, 0.f, 0.f, 0.f};

  stage(0, 0);
  for (int t = 0; t < NT; ++t) {
    int p = t & 1;
    if (t + 1 < NT) {
      stage(t + 1, p ^ 1);  // issue early; lands during this tile's compute
      asm volatile("s_waitcnt vmcnt(8)" ::: "memory");  // tile t arrived; t+1 in flight
    } else {
      asm volatile("s_waitcnt vmcnt(0)" ::: "memory");
    }
    __builtin_amdgcn_s_barrier();
    const char* base = (const char*)lds[p];
    bf16x8 afA[8], bgA[4], afB[8], bgB[4];
#pragma unroll
    for (int mi = 0; mi < 8; ++mi) afA[mi] = *(const bf16x8*)(base + aoff0[mi]);
#pragma unroll
    for (int ni = 0; ni < 4; ++ni) bgA[ni] = *(const bf16x8*)(base + boff0[ni]);
#pragma unroll
    for (int mi = 0; mi < 8; ++mi) afB[mi] = *(const bf16x8*)(base + aoff1[mi]);
#pragma unroll
    for (int ni = 0; ni < 4; ++ni) bgB[ni] = *(const bf16x8*)(base + boff1[ni]);
    __builtin_amdgcn_s_setprio(1);
#pragma unroll
    for (int mi = 0; mi < 8; ++mi)
#pragma unroll
      for (int ni = 0; ni < 4; ++ni)
        acc[mi][ni] =
            __builtin_amdgcn_mfma_f32_16x16x32_bf16(afA[mi], bgA[ni], acc[mi][ni], 0, 0, 0);
#pragma unroll
    for (int mi = 0; mi < 8; ++mi)
#pragma unroll
      for (int ni = 0; ni < 4; ++ni)
        acc[mi][ni] =
            __builtin_amdgcn_mfma_f32_16x16x32_bf16(afB[mi], bgB[ni], acc[mi][ni], 0, 0, 0);
    __builtin_amdgcn_s_setprio(0);
    __builtin_amdgcn_s_barrier();  // all reads of buf p done before stage(t+2) writes it
  }
  // epilogue: D row=(lane>>4)*4+j, col=lane&15
#pragma unroll
  for (int mi = 0; mi < 8; ++mi) {
#pragma unroll
    for (int j = 0; j < 4; ++j) {
      int row = m0 + (wr << 7) + (mi << 4) + ((lane >> 4) << 2) + j;
      size_t bofs = (size_t)row * N + n0 + (wc << 6);
#pragma unroll
      for (int ni = 0; ni < 4; ++ni)
        C[bofs + (ni << 4) + (lane & 15)] = f2b(acc[mi][ni][j]);
    }
  }
}

// ---------------- SRU bidirectional scan ----------------
template <int KC, typename OT>
__global__ void sru_scan_kernel(const ushort* __restrict__ u, const float* __restrict__ bias,
                                const ushort* __restrict__ xres, OT* __restrict__ hout,
                                float* __restrict__ cout) {
  const int L = 256, B = 64, H = 512;
  int idx = blockIdx.x * 256 + threadIdx.x;
  int h = idx & (H - 1);
  int dir = (idx >> 9) & 1;
  int b = idx >> 10;
  float bfg = bias[dir * H + h];
  float brg = bias[2 * H + dir * H + h];
  const size_t ustep = (size_t)B * 2 * H * KC;
  const ushort* ubase = u + ((size_t)b * 2 + dir) * H * KC + (size_t)h * KC;
  const size_t hstep = (size_t)B * 2 * H;
  const size_t hoff = (size_t)b * 2 * H + (size_t)dir * H + h;
  float c = 0.f;
#pragma unroll 16
  for (int s = 0; s < L; ++s) {
    int t = dir ? (L - 1 - s) : s;
    const ushort* up = ubase + (size_t)t * ustep;
    float xt, fg, rg, xr;
    if (KC == 4) {
      uint2 v = *(const uint2*)up;
      xt = b2f((ushort)(v.x & 0xffff));
      fg = b2f((ushort)(v.x >> 16));
      rg = b2f((ushort)(v.y & 0xffff));
      xr = b2f((ushort)(v.y >> 16));
    } else {
      xt = b2f(up[0]);
      fg = b2f(up[1]);
      rg = b2f(up[2]);
      xr = b2f(xres[hoff + (size_t)t * hstep]);
    }
    float f = sigm_fast(fg + bfg);
    float r = sigm_fast(rg + brg);
    c = f * c + (1.f - f) * xt;
    float hv = r * tanh_fast(c) + (1.f - r) * xr;
    store_h(hout + hoff + (size_t)t * hstep, hv);
  }
  cout[(size_t)b * 2 * H + (size_t)dir * H + h] = c;
}

// ---------------- dense_hidden ----------------
__global__ __launch_bounds__(512) void dense_kernel(
    const float* __restrict__ c12, const ushort* __restrict__ WdT,
    const float* __restrict__ bd, float* __restrict__ out) {
  int row = blockIdx.x;
  int j = threadIdx.x;
  const float* c = c12 + (size_t)row * 1024;
  float acc = bd[j];
#pragma unroll 8
  for (int k = 0; k < 1024; ++k) acc += c[k] * b2f(WdT[(size_t)k * 512 + j]);
  out[(size_t)row * 512 + j] = acc;
}

extern "C" void kernel_launch(void* const* d_in, const int* in_sizes, int n_in,
                              void* d_out, int out_size, void* d_ws, size_t ws_size,
                              hipStream_t stream) {
  const int* tok = (const int*)d_in[0];
  const float* emb = (const float*)d_in[1];
  const float* W0 = (const float*)d_in[2];
  const float* b0 = (const float*)d_in[3];
  const float* W1 = (const float*)d_in[4];
  const float* b1 = (const float*)d_in[5];
  const float* Wd = (const float*)d_in[6];
  const float* bd = (const float*)d_in[7];
  float* out = (float*)d_out;

  char* ws = (char*)d_ws;
  ushort* x = (ushort*)ws;                        //  16,777,216 B
  ushort* W0T = (ushort*)(ws + 16777216);         //   4,194,304 B
  ushort* W1T = (ushort*)(ws + 20971520);         //   6,291,456 B
  ushort* u = (ushort*)(ws + 27262976);           // 134,217,728 B (u0/u1 aliased)
  ushort* h1 = (ushort*)(ws + 161480704);         //  33,554,432 B
  float* c12 = (float*)(ws + 195035136);          //     524,288 B
  ushort* WdT = (ushort*)(ws + 27262976 + 100663296);  // dead tail of u after scan1

  transpose_kernel<<<dim3(128, 16), 256, 0, stream>>>(W0, W0T, 512, 4096);
  transpose_kernel<<<dim3(96, 32), 256, 0, stream>>>(W1, W1T, 1024, 3072);
  embed_kernel<<<4096, 256, 0, stream>>>(tok, emb, x);
  // u0 = x @ W0   (16384 x 4096), 64 Mtiles x 16 Ntiles
  gemm_bt4_kernel<<<1024, 512, 0, stream>>>(x, W0T, u, 16384, 4096, 512);
  sru_scan_kernel<4, ushort><<<256, 256, 0, stream>>>(u, b0, (const ushort*)nullptr, h1, c12);
  // u1 = h1 @ W1  (16384 x 3072), 64 x 12
  gemm_bt4_kernel<<<768, 512, 0, stream>>>(h1, W1T, u, 16384, 3072, 1024);
  sru_scan_kernel<3, float><<<256, 256, 0, stream>>>(u, b1, h1, out, c12 + 65536);
  transpose_kernel<<<dim3(32, 16), 256, 0, stream>>>(Wd, WdT, 512, 1024);
  dense_kernel<<<128, 512, 0, stream>>>(c12, WdT, bd, out + 16777216);
}

// Round 10
// 365.290 us; speedup vs baseline: 1.2474x; 1.2474x over previous
//
#include <hip/hip_runtime.h>

typedef __attribute__((ext_vector_type(8))) short bf16x8;
typedef __attribute__((ext_vector_type(4))) float f32x4;

__device__ __forceinline__ float b2f(ushort s) { return __uint_as_float(((uint)s) << 16); }
__device__ __forceinline__ ushort f2b(float f) {
  uint u = __float_as_uint(f);
  u += 0x7fff + ((u >> 16) & 1);   // RNE
  return (ushort)(u >> 16);
}

__device__ __forceinline__ void store_h(float* p, float v) { *p = v; }
__device__ __forceinline__ void store_h(ushort* p, float v) { *p = f2b(v); }

__device__ __forceinline__ float sigm_fast(float x) { return 1.f / (1.f + __expf(-x)); }
__device__ __forceinline__ float tanh_fast(float c) {
  float e = __expf(-2.f * fabsf(c));
  float t = (1.f - e) / (1.f + e);
  return copysignf(t, c);
}

// ---------------- transpose+cast: in (R x C) f32 -> out (C x R) bf16 ----------------
__global__ void transpose_kernel(const float* __restrict__ in, ushort* __restrict__ out,
                                 int R, int C) {
  __shared__ ushort tile[32][33];
  int bc = blockIdx.x << 5;
  int br = blockIdx.y << 5;
  int tx = threadIdx.x & 31;
  int ty = threadIdx.x >> 5;  // 0..7
#pragma unroll
  for (int i = 0; i < 32; i += 8)
    tile[ty + i][tx] = f2b(in[(size_t)(br + ty + i) * C + bc + tx]);
  __syncthreads();
#pragma unroll
  for (int i = 0; i < 32; i += 8)
    out[(size_t)(bc + ty + i) * R + br + tx] = tile[tx][ty + i];
}

// ---------------- embedding gather+cast ----------------
__global__ void embed_kernel(const int* __restrict__ tok, const float* __restrict__ emb,
                             ushort* __restrict__ x) {
  int tid = threadIdx.x;
  int r = (blockIdx.x << 2) + (tid >> 6);
  int c = (tid & 63) << 3;
  int t = tok[r];
  const float* src = emb + ((size_t)t << 9) + c;
  float4 a = *(const float4*)src;
  float4 b = *(const float4*)(src + 4);
  uint4 o;
  o.x = (uint)f2b(a.x) | ((uint)f2b(a.y) << 16);
  o.y = (uint)f2b(a.z) | ((uint)f2b(a.w) << 16);
  o.z = (uint)f2b(b.x) | ((uint)f2b(b.y) << 16);
  o.w = (uint)f2b(b.z) | ((uint)f2b(b.w) << 16);
  *(uint4*)(x + ((size_t)r << 9) + c) = o;
}

// ---------------- GEMM v5: 256x256 tile, BK=64, 2-buffer counted-vmcnt pipeline ------
// C(MxN) bf16 = A(MxK) * BT(NxK), 512 threads = 8 waves (2M x 4N), per-wave 128x64 out.
// Explicit fragment double-buffer (afA/bgA vs afB/bgB): kk1's 12 ds_read_b128 overlap
// kk0's 32-MFMA cluster.
// R8/R9 lesson: demand was 267 regs (acc128+frags96+offsets24+addr16+misc) > the hard
// 256/wave cap at 8 waves/CU -> ~11-reg spill (WRITE_SIZE +15MB), MfmaUtil 26%.
// Fix: addressing algebra. row&7 == lane&7 for A and B rows, so swizzled offset =
// row*128 + (k ^ swz) and the mi/ni terms are compile-time immediates: 24 offset regs
// -> 4 base regs (aB0, aB1=aB0^64, bB0, bB1) + ds_read offset:mi*2048. Staging offsets
// (row*K+col per sub) hoisted: 4 regs, +uniform t*64 per tile. Total ~247 <= 256.
// LDS: 2 x 64 KiB; staging global_load_lds w=16, linear dest + inverse-swizzled src;
// reads swizzled byte ^= (row&7)<<4 (0 conflicts). XCD-chunked 8x4 supertile mapping.
__global__ __launch_bounds__(512, 1) void gemm_bt5_kernel(
    const ushort* __restrict__ A, const ushort* __restrict__ BT,
    ushort* __restrict__ C, int M, int N, int K) {
  __shared__ char lds[2][65536];  // per buf: A bytes [0,32768), B bytes [32768,65536)
  const int tid = threadIdx.x;
  const int lane = tid & 63;
  const int wave = tid >> 6;  // 0..7
  const int wr = wave >> 2;   // 0..1
  const int wc = wave & 3;    // 0..3

  // supertile mapping (requires gridDim.x % 256 == 0; true for 1024 and 768)
  const int xcd = blockIdx.x & 7;
  const int l = blockIdx.x >> 3;
  const int s = xcd * (gridDim.x >> 8) + (l >> 5);  // supertile id (8mt x 4nt)
  const int uu = l & 31;
  const int mt = ((s & 7) << 3) + (uu & 7);
  const int nt = ((s >> 3) << 2) + (uu >> 3);
  const int m0 = mt << 8;
  const int n0 = nt << 8;
  const int NT = K >> 6;

  // ds_read bases (4 regs total; mi/ni become offset: immediates)
  const int k0s = ((lane >> 4) << 4) ^ ((lane & 7) << 4);  // k0b ^ swz, bits 4-6
  const int aB0 = (wr << 14) + ((lane & 15) << 7) + k0s;
  const int aB1 = aB0 ^ 64;  // kk1 (k += 32 bf16 = 64 bytes; bit 6 clean XOR)
  const int bB0 = 32768 + (wc << 13) + ((lane & 15) << 7) + k0s;
  const int bB1 = bB0 ^ 64;

  // staging source offsets (elements), t-invariant; shared by A and B regions
  int srcoff[4];
#pragma unroll
  for (int sub = 0; sub < 4; ++sub) {
    int off = (sub << 13) + (tid << 4);             // byte within 32KiB region
    int row = off >> 7;                             // 0..255
    int col = ((off & 127) ^ ((row & 7) << 4)) >> 1;
    srcoff[sub] = row * K + col;
  }
  const ushort* Abase = A + (size_t)m0 * K;
  const ushort* Bbase = BT + (size_t)n0 * K;

  auto stage = [&](int t, int p) {
    const int tk = t << 6;
#pragma unroll
    for (int i = 0; i < 8; ++i) {
      int sub = i & 3;
      const ushort* src = ((i < 4) ? Abase : Bbase) + srcoff[sub] + tk;
      char* dst = lds[p] + ((i < 4) ? 0 : 32768) + (sub << 13) + (wave << 10);
      __builtin_amdgcn_global_load_lds(
          (const __attribute__((address_space(1))) void*)src,
          (__attribute__((address_space(3))) void*)dst, 16, 0, 0);
    }
  };

  f32x4 acc[8][4];
#pragma unroll
  for (int i = 0; i < 8; ++i)
#pragma unroll
    for (int j = 0; j < 4; ++j) acc[i][j] = (f32x4){0.f, 0.f, 0.f, 0.f};

  stage(0, 0);
  for (int t = 0; t < NT; ++t) {
    int p = t & 1;
    if (t + 1 < NT) {
      stage(t + 1, p ^ 1);  // issue early; lands during this tile's compute
      asm volatile("s_waitcnt vmcnt(8)" ::: "memory");  // tile t arrived; t+1 in flight
    } else {
      asm volatile("s_waitcnt vmcnt(0)" ::: "memory");
    }
    __builtin_amdgcn_s_barrier();
    const char* base = (const char*)lds[0] + (p << 16);
    bf16x8 afA[8], bgA[4], afB[8], bgB[4];
#pragma unroll
    for (int mi = 0; mi < 8; ++mi) afA[mi] = *(const bf16x8*)(base + aB0 + (mi << 11));
#pragma unroll
    for (int ni = 0; ni < 4; ++ni) bgA[ni] = *(const bf16x8*)(base + bB0 + (ni << 11));
#pragma unroll
    for (int mi = 0; mi < 8; ++mi) afB[mi] = *(const bf16x8*)(base + aB1 + (mi << 11));
#pragma unroll
    for (int ni = 0; ni < 4; ++ni) bgB[ni] = *(const bf16x8*)(base + bB1 + (ni << 11));
    __builtin_amdgcn_s_setprio(1);
#pragma unroll
    for (int mi = 0; mi < 8; ++mi)
#pragma unroll
      for (int ni = 0; ni < 4; ++ni)
        acc[mi][ni] =
            __builtin_amdgcn_mfma_f32_16x16x32_bf16(afA[mi], bgA[ni], acc[mi][ni], 0, 0, 0);
#pragma unroll
    for (int mi = 0; mi < 8; ++mi)
#pragma unroll
      for (int ni = 0; ni < 4; ++ni)
        acc[mi][ni] =
            __builtin_amdgcn_mfma_f32_16x16x32_bf16(afB[mi], bgB[ni], acc[mi][ni], 0, 0, 0);
    __builtin_amdgcn_s_setprio(0);
    __builtin_amdgcn_s_barrier();  // all reads of buf p done before stage(t+2) writes it
  }
  // epilogue: D row=(lane>>4)*4+j, col=lane&15
#pragma unroll
  for (int mi = 0; mi < 8; ++mi) {
#pragma unroll
    for (int j = 0; j < 4; ++j) {
      int row = m0 + (wr << 7) + (mi << 4) + ((lane >> 4) << 2) + j;
      size_t bofs = (size_t)row * N + n0 + (wc << 6);
#pragma unroll
      for (int ni = 0; ni < 4; ++ni)
        C[bofs + (ni << 4) + (lane & 15)] = f2b(acc[mi][ni][j]);
    }
  }
}

// ---------------- SRU bidirectional scan ----------------
template <int KC, typename OT>
__global__ void sru_scan_kernel(const ushort* __restrict__ u, const float* __restrict__ bias,
                                const ushort* __restrict__ xres, OT* __restrict__ hout,
                                float* __restrict__ cout) {
  const int L = 256, B = 64, H = 512;
  int idx = blockIdx.x * 256 + threadIdx.x;
  int h = idx & (H - 1);
  int dir = (idx >> 9) & 1;
  int b = idx >> 10;
  float bfg = bias[dir * H + h];
  float brg = bias[2 * H + dir * H + h];
  const size_t ustep = (size_t)B * 2 * H * KC;
  const ushort* ubase = u + ((size_t)b * 2 + dir) * H * KC + (size_t)h * KC;
  const size_t hstep = (size_t)B * 2 * H;
  const size_t hoff = (size_t)b * 2 * H + (size_t)dir * H + h;
  float c = 0.f;
#pragma unroll 16
  for (int s = 0; s < L; ++s) {
    int t = dir ? (L - 1 - s) : s;
    const ushort* up = ubase + (size_t)t * ustep;
    float xt, fg, rg, xr;
    if (KC == 4) {
      uint2 v = *(const uint2*)up;
      xt = b2f((ushort)(v.x & 0xffff));
      fg = b2f((ushort)(v.x >> 16));
      rg = b2f((ushort)(v.y & 0xffff));
      xr = b2f((ushort)(v.y >> 16));
    } else {
      xt = b2f(up[0]);
      fg = b2f(up[1]);
      rg = b2f(up[2]);
      xr = b2f(xres[hoff + (size_t)t * hstep]);
    }
    float f = sigm_fast(fg + bfg);
    float r = sigm_fast(rg + brg);
    c = f * c + (1.f - f) * xt;
    float hv = r * tanh_fast(c) + (1.f - r) * xr;
    store_h(hout + hoff + (size_t)t * hstep, hv);
  }
  cout[(size_t)b * 2 * H + (size_t)dir * H + h] = c;
}

// ---------------- dense_hidden ----------------
__global__ __launch_bounds__(512) void dense_kernel(
    const float* __restrict__ c12, const ushort* __restrict__ WdT,
    const float* __restrict__ bd, float* __restrict__ out) {
  int row = blockIdx.x;
  int j = threadIdx.x;
  const float* c = c12 + (size_t)row * 1024;
  float acc = bd[j];
#pragma unroll 8
  for (int k = 0; k < 1024; ++k) acc += c[k] * b2f(WdT[(size_t)k * 512 + j]);
  out[(size_t)row * 512 + j] = acc;
}

extern "C" void kernel_launch(void* const* d_in, const int* in_sizes, int n_in,
                              void* d_out, int out_size, void* d_ws, size_t ws_size,
                              hipStream_t stream) {
  const int* tok = (const int*)d_in[0];
  const float* emb = (const float*)d_in[1];
  const float* W0 = (const float*)d_in[2];
  const float* b0 = (const float*)d_in[3];
  const float* W1 = (const float*)d_in[4];
  const float* b1 = (const float*)d_in[5];
  const float* Wd = (const float*)d_in[6];
  const float* bd = (const float*)d_in[7];
  float* out = (float*)d_out;

  char* ws = (char*)d_ws;
  ushort* x = (ushort*)ws;                        //  16,777,216 B
  ushort* W0T = (ushort*)(ws + 16777216);         //   4,194,304 B
  ushort* W1T = (ushort*)(ws + 20971520);         //   6,291,456 B
  ushort* u = (ushort*)(ws + 27262976);           // 134,217,728 B (u0/u1 aliased)
  ushort* h1 = (ushort*)(ws + 161480704);         //  33,554,432 B
  float* c12 = (float*)(ws + 195035136);          //     524,288 B
  ushort* WdT = (ushort*)(ws + 27262976 + 100663296);  // dead tail of u after scan1

  transpose_kernel<<<dim3(128, 16), 256, 0, stream>>>(W0, W0T, 512, 4096);
  transpose_kernel<<<dim3(96, 32), 256, 0, stream>>>(W1, W1T, 1024, 3072);
  embed_kernel<<<4096, 256, 0, stream>>>(tok, emb, x);
  // u0 = x @ W0   (16384 x 4096), 64 Mtiles x 16 Ntiles
  gemm_bt5_kernel<<<1024, 512, 0, stream>>>(x, W0T, u, 16384, 4096, 512);
  sru_scan_kernel<4, ushort><<<256, 256, 0, stream>>>(u, b0, (const ushort*)nullptr, h1, c12);
  // u1 = h1 @ W1  (16384 x 3072), 64 x 12
  gemm_bt5_kernel<<<768, 512, 0, stream>>>(h1, W1T, u, 16384, 3072, 1024);
  sru_scan_kernel<3, float><<<256, 256, 0, stream>>>(u, b1, h1, out, c12 + 65536);
  transpose_kernel<<<dim3(32, 16), 256, 0, stream>>>(Wd, WdT, 512, 1024);
  dense_kernel<<<128, 512, 0, stream>>>(c12, WdT, bd, out + 16777216);
}